// Round 1
// baseline (64991.254 us; speedup 1.0000x reference)
//
#include <hip/hip_runtime.h>

// GRU with softmax gates. SEQ=512, BS=128, IN=512, H=1024, D=1536.
// Round 1: single persistent cooperative kernel.
//   - weights pinned in LDS: 192 blocks x 16 rows x 1536 bf16 (padded +8 -> conflict-free)
//   - 2 grid barriers/step (softmax denominator factored out of gemm_h)
//   - x-part of each gate GEMM prefetched into registers during the opposite phase
//   - roles: blk 0..63 = z cols, 64..127 = r cols, 128..191 = h cols
// Workspace ~74.6 MiB.

#define SEQ 512
#define BS 128
#define IN_DIM 512
#define H_DIM 1024
#define DTOT 1536
#define NB 192
#define NT 512
#define WPAD 1544   // 1536 + 8 shorts pad: row stride 3088B -> bank stride 4 -> 2-way (free)

typedef __attribute__((ext_vector_type(8))) short bfrag;   // 8 x bf16
typedef __attribute__((ext_vector_type(4))) float facc;    // 4 x f32

__device__ __forceinline__ unsigned short f2bf(float f) {
    unsigned int u = __float_as_uint(f);
    unsigned int r = (u + 0x7FFFu + ((u >> 16) & 1u)) >> 16;
    return (unsigned short)r;
}

// ---------------- one-time converts ----------------

__global__ void cvt_w(const float* __restrict__ Wz, const float* __restrict__ Wr,
                      const float* __restrict__ Wh,
                      unsigned short* __restrict__ wzr, unsigned short* __restrict__ wh) {
    size_t i = (size_t)blockIdx.x * 256 + threadIdx.x;
    if (i >= (size_t)3072 * DTOT) return;
    int k = (int)(i % DTOT);
    int n = (int)(i / DTOT);
    float v;
    if (n < 1024)       v = Wz[(size_t)k * H_DIM + n];
    else if (n < 2048)  v = Wr[(size_t)k * H_DIM + (n - 1024)];
    else                v = Wh[(size_t)k * H_DIM + (n - 2048)];
    unsigned short b = f2bf(v);
    if (n < 2048) wzr[(size_t)n * DTOT + k] = b;
    else          wh[(size_t)(n - 2048) * DTOT + k] = b;
}

__global__ void cvt_x(const float4* __restrict__ x, unsigned long long* __restrict__ xb) {
    size_t i = (size_t)blockIdx.x * 256 + threadIdx.x;
    if (i >= (size_t)SEQ * BS * IN_DIM / 4) return;
    float4 v = x[i];
    unsigned long long p = (unsigned long long)f2bf(v.x)
                         | ((unsigned long long)f2bf(v.y) << 16)
                         | ((unsigned long long)f2bf(v.z) << 32)
                         | ((unsigned long long)f2bf(v.w) << 48);
    xb[i] = p;
}

__global__ void init_h(const float* __restrict__ h0, float* __restrict__ hf,
                       unsigned short* __restrict__ hb, unsigned* __restrict__ bar) {
    int i = blockIdx.x * 256 + threadIdx.x;
    if (i < 2) bar[i] = 0u;           // barrier cnt/gen reset each replay
    if (i >= BS * H_DIM) return;
    float v = h0[i];
    hf[i] = v;
    hb[i] = f2bf(v);
}

// ---------------- persistent kernel ----------------

struct PArgs {
    const unsigned short* wzr;   // [2048][1536]
    const unsigned short* wh;    // [1024][1536]
    const unsigned short* xb;    // [512][128][512]
    const float* bz;
    const float* br;
    const float* bh;
    float* hf;                   // [128][1024] fp32 master h
    unsigned short* hb;          // [128][1024] bf16 h
    unsigned short* ub;          // [128][1024] bf16 u = exp(pre_r)*h (unnormalized)
    float* ez;                   // [128][1024] exp(pre_z) (unnormalized)
    float* szp;                  // [64][128] partial row-sums of exp(pre_z)
    float* srp;                  // [64][128] partial row-sums of exp(pre_r)
    float* out;                  // [512][128][1024]
    unsigned* bar;               // [2] = {cnt, gen}
};

__device__ __forceinline__ void gridbar(unsigned* cnt, unsigned* gen) {
    __builtin_amdgcn_fence(__ATOMIC_RELEASE, "agent");
    __syncthreads();
    if (threadIdx.x == 0) {
        unsigned g = __hip_atomic_load(gen, __ATOMIC_RELAXED, __HIP_MEMORY_SCOPE_AGENT);
        unsigned a = __hip_atomic_fetch_add(cnt, 1u, __ATOMIC_ACQ_REL, __HIP_MEMORY_SCOPE_AGENT);
        if (a == (unsigned)(NB - 1)) {
            __hip_atomic_store(cnt, 0u, __ATOMIC_RELAXED, __HIP_MEMORY_SCOPE_AGENT);
            __hip_atomic_store(gen, g + 1u, __ATOMIC_RELEASE, __HIP_MEMORY_SCOPE_AGENT);
        } else {
            while (__hip_atomic_load(gen, __ATOMIC_RELAXED, __HIP_MEMORY_SCOPE_AGENT) == g) {
                __builtin_amdgcn_s_sleep(2);
            }
        }
    }
    __syncthreads();
    __builtin_amdgcn_fence(__ATOMIC_ACQUIRE, "agent");
}

__global__ __launch_bounds__(NT, 1) void gru_persistent(PArgs p) {
    __shared__ unsigned short wlds[16][WPAD];   // this block's 16 weight rows
    __shared__ float redz[4][BS];
    __shared__ float redr[4][BS];
    __shared__ float invz[BS];
    __shared__ float invr[BS];

    const int tid  = threadIdx.x;
    const int lane = tid & 63;
    const int wv   = tid >> 6;        // wave 0..7, owns rows wv*16..+16
    const int lm   = lane & 15;
    const int kq   = lane >> 4;
    const int blk  = blockIdx.x;
    const bool is_h = (blk >= 128);
    const bool is_z = (blk < 64);
    const int arow = wv * 16 + lm;    // A-operand row this lane loads

    // ---- stage weights into LDS (one time) ----
    const unsigned short* wsrc = is_h ? (p.wh + (size_t)(blk - 128) * 16 * DTOT)
                                      : (p.wzr + (size_t)blk * 16 * DTOT);
    for (int c = tid; c < 16 * 192; c += NT) {     // 192 x 16B chunks per row
        int n = c / 192;
        int o = (c % 192) * 8;
        *(float4*)&wlds[n][o] = *(const float4*)(wsrc + (size_t)n * DTOT + o);
    }
    float bias_l;
    if (is_h) {
        bias_l = p.bh[(blk - 128) * 16 + lm];
    } else {
        int n = blk * 16 + lm;
        bias_l = (n < H_DIM) ? p.bz[n] : p.br[n - H_DIM];
    }
    __syncthreads();

    unsigned* cnt = p.bar;
    unsigned* gen = p.bar + 1;

    // persistent register accumulator for the x-part (K=512) of this block's GEMM
    facc accx = (facc){0.f, 0.f, 0.f, 0.f};
    if (!is_h) {    // preamble: x-part of pre_zr for t=0
        const unsigned short* ax = p.xb + (size_t)arow * IN_DIM + kq * 8;
        #pragma unroll
        for (int kc = 0; kc < IN_DIM; kc += 32) {
            bfrag a = *(const bfrag*)(ax + kc);
            bfrag b = *(const bfrag*)&wlds[lm][H_DIM + kc + kq * 8];
            accx = __builtin_amdgcn_mfma_f32_16x16x32_bf16(a, b, accx, 0, 0, 0);
        }
    }

    for (int t = 0; t < SEQ; ++t) {
        const unsigned short* xb_t = p.xb + (size_t)t * BS * IN_DIM;

        // ================= phase A =================
        if (!is_h) {
            // pre = accx + h @ W[:,0:1024]; e = exp(pre + bias); partial row sums
            facc accA = accx;
            facc accB = (facc){0.f, 0.f, 0.f, 0.f};
            const unsigned short* ah = p.hb + (size_t)arow * H_DIM + kq * 8;
            #pragma unroll 4
            for (int kc = 0; kc < H_DIM; kc += 64) {
                bfrag a0 = *(const bfrag*)(ah + kc);
                bfrag b0 = *(const bfrag*)&wlds[lm][kc + kq * 8];
                accA = __builtin_amdgcn_mfma_f32_16x16x32_bf16(a0, b0, accA, 0, 0, 0);
                bfrag a1 = *(const bfrag*)(ah + kc + 32);
                bfrag b1 = *(const bfrag*)&wlds[lm][kc + 32 + kq * 8];
                accB = __builtin_amdgcn_mfma_f32_16x16x32_bf16(a1, b1, accB, 0, 0, 0);
            }
            accA = accA + accB;
            float e[4], sf[4];
            #pragma unroll
            for (int r = 0; r < 4; ++r) {
                e[r] = expf(accA[r] + bias_l);
                float s = e[r];
                s += __shfl_xor(s, 1, 64);
                s += __shfl_xor(s, 2, 64);
                s += __shfl_xor(s, 4, 64);
                s += __shfl_xor(s, 8, 64);
                sf[r] = s;          // sum over this block's 16 cols, per row
            }
            if (is_z) {
                const int col = blk * 16 + lm;
                #pragma unroll
                for (int r = 0; r < 4; ++r) {
                    const int rr = wv * 16 + kq * 4 + r;
                    p.ez[(size_t)rr * H_DIM + col] = e[r];
                }
                if (lm == 0) {
                    #pragma unroll
                    for (int r = 0; r < 4; ++r)
                        p.szp[(size_t)blk * BS + wv * 16 + kq * 4 + r] = sf[r];
                }
            } else {
                const int col = (blk - 64) * 16 + lm;
                #pragma unroll
                for (int r = 0; r < 4; ++r) {
                    const int rr = wv * 16 + kq * 4 + r;
                    float u = e[r] * p.hf[(size_t)rr * H_DIM + col];
                    p.ub[(size_t)rr * H_DIM + col] = f2bf(u);
                }
                if (lm == 0) {
                    #pragma unroll
                    for (int r = 0; r < 4; ++r)
                        p.srp[(size_t)(blk - 64) * BS + wv * 16 + kq * 4 + r] = sf[r];
                }
            }
        } else {
            // h-blocks: x-part of pre_h for this step into registers
            accx = (facc){0.f, 0.f, 0.f, 0.f};
            const unsigned short* ax = xb_t + (size_t)arow * IN_DIM + kq * 8;
            #pragma unroll
            for (int kc = 0; kc < IN_DIM; kc += 32) {
                bfrag a = *(const bfrag*)(ax + kc);
                bfrag b = *(const bfrag*)&wlds[lm][H_DIM + kc + kq * 8];
                accx = __builtin_amdgcn_mfma_f32_16x16x32_bf16(a, b, accx, 0, 0, 0);
            }
        }
        gridbar(cnt, gen);

        // ================= phase B =================
        if (is_h) {
            // combine softmax partial sums (redundant per h-block)
            {
                const int b = tid & 127;
                const int g = tid >> 7;    // 0..3
                float az = 0.f, ar = 0.f;
                #pragma unroll
                for (int j = 0; j < 16; ++j) {
                    az += p.szp[(size_t)(g * 16 + j) * BS + b];
                    ar += p.srp[(size_t)(g * 16 + j) * BS + b];
                }
                redz[g][b] = az;
                redr[g][b] = ar;
            }
            __syncthreads();
            if (tid < BS) {
                invz[tid] = 1.f / (redz[0][tid] + redz[1][tid] + redz[2][tid] + redz[3][tid]);
                invr[tid] = 1.f / (redr[0][tid] + redr[1][tid] + redr[2][tid] + redr[3][tid]);
            }
            __syncthreads();
            // num = u @ Wh[:,0:1024]; pre_h = num/s_r + accx + bh
            facc accA = (facc){0.f, 0.f, 0.f, 0.f};
            facc accB = (facc){0.f, 0.f, 0.f, 0.f};
            const unsigned short* au = p.ub + (size_t)arow * H_DIM + kq * 8;
            #pragma unroll 4
            for (int kc = 0; kc < H_DIM; kc += 64) {
                bfrag a0 = *(const bfrag*)(au + kc);
                bfrag b0 = *(const bfrag*)&wlds[lm][kc + kq * 8];
                accA = __builtin_amdgcn_mfma_f32_16x16x32_bf16(a0, b0, accA, 0, 0, 0);
                bfrag a1 = *(const bfrag*)(au + kc + 32);
                bfrag b1 = *(const bfrag*)&wlds[lm][kc + 32 + kq * 8];
                accB = __builtin_amdgcn_mfma_f32_16x16x32_bf16(a1, b1, accB, 0, 0, 0);
            }
            accA = accA + accB;
            const int col = (blk - 128) * 16 + lm;
            float* out_t = p.out + (size_t)t * BS * H_DIM;
            #pragma unroll
            for (int r = 0; r < 4; ++r) {
                const int rr = wv * 16 + kq * 4 + r;
                const size_t idx = (size_t)rr * H_DIM + col;
                float pre = accA[r] * invr[rr] + accx[r] + bias_l;
                float th = tanhf(pre);
                float zv = p.ez[idx] * invz[rr];
                float hv = p.hf[idx];
                float hn = fmaf(zv, th - hv, hv);
                p.hf[idx] = hn;
                p.hb[idx] = f2bf(hn);
                out_t[idx] = hn;
            }
        } else if (t + 1 < SEQ) {
            // zr-blocks: prefetch x-part of pre_zr for t+1
            accx = (facc){0.f, 0.f, 0.f, 0.f};
            const unsigned short* ax = p.xb + (size_t)(t + 1) * BS * IN_DIM
                                       + (size_t)arow * IN_DIM + kq * 8;
            #pragma unroll
            for (int kc = 0; kc < IN_DIM; kc += 32) {
                bfrag a = *(const bfrag*)(ax + kc);
                bfrag b = *(const bfrag*)&wlds[lm][H_DIM + kc + kq * 8];
                accx = __builtin_amdgcn_mfma_f32_16x16x32_bf16(a, b, accx, 0, 0, 0);
            }
        }
        gridbar(cnt, gen);
    }
}

// ---------------- launch ----------------

extern "C" void kernel_launch(void* const* d_in, const int* in_sizes, int n_in,
                              void* d_out, int out_size, void* d_ws, size_t ws_size,
                              hipStream_t stream) {
    const float* x  = (const float*)d_in[0];
    const float* h0 = (const float*)d_in[1];
    const float* Wz = (const float*)d_in[2];
    const float* bz = (const float*)d_in[3];
    const float* Wr = (const float*)d_in[4];
    const float* br = (const float*)d_in[5];
    const float* Wh = (const float*)d_in[6];
    const float* bh = (const float*)d_in[7];
    float* out = (float*)d_out;

    char* base = (char*)d_ws;
    unsigned short* wzr_t = (unsigned short*)(base);                 //  6,291,456
    unsigned short* wh_t  = (unsigned short*)(base + 6291456);       //  3,145,728
    unsigned short* x_b   = (unsigned short*)(base + 9437184);       // 67,108,864
    float*          h_f32 = (float*)         (base + 76546048);      //    524,288
    unsigned short* h_b   = (unsigned short*)(base + 77070336);      //    262,144
    unsigned short* u_b   = (unsigned short*)(base + 77332480);      //    262,144
    float*          ez    = (float*)         (base + 77594624);      //    524,288
    float*          szp   = (float*)         (base + 78118912);      //     32,768
    float*          srp   = (float*)         (base + 78151680);      //     32,768
    unsigned*       bar   = (unsigned*)      (base + 78184448);      //        256
    // total ~74.6 MiB

    cvt_w<<<(3072 * DTOT + 255) / 256, 256, 0, stream>>>(Wz, Wr, Wh, wzr_t, wh_t);
    cvt_x<<<((SEQ * BS * IN_DIM / 4) + 255) / 256, 256, 0, stream>>>(
        (const float4*)x, (unsigned long long*)x_b);
    init_h<<<(BS * H_DIM + 255) / 256, 256, 0, stream>>>(h0, h_f32, h_b, bar);

    PArgs pa;
    pa.wzr = wzr_t; pa.wh = wh_t; pa.xb = x_b;
    pa.bz = bz; pa.br = br; pa.bh = bh;
    pa.hf = h_f32; pa.hb = h_b; pa.ub = u_b; pa.ez = ez;
    pa.szp = szp; pa.srp = srp; pa.out = out; pa.bar = bar;
    void* kp[] = { &pa };
    hipLaunchCooperativeKernel(reinterpret_cast<void*>(gru_persistent),
                               dim3(NB), dim3(NT), kp, 0, stream);
}